// Round 1
// 2755.584 us; speedup vs baseline: 1.0868x; 1.0868x over previous
//
#include <hip/hip_runtime.h>

// ---------------------------------------------------------------------------
// Decoder fwd: B=2, L=2048, D=1024, H=16 (dh=64), V=32000, N_LAYER=4, FFN=2D.
// f16 MFMA everywhere; residual stream kept f32 in ws. Weights transposed+
// converted to f16 per call (inputs are re-pristined each timed call anyway).
// d_out (524 MB) doubles as transient scratch until the final logits GEMM.
// ws requirement: ~90.8 MB.
// R1: +XCD-aware block swizzle in GEMMs (T1), +128x64-tile GEMM for N=1024
//     (Wo/Wdown were 256 blocks = 1 wave/SIMD), +LDS XOR swizzles in attn
//     (Ks read was a 16-lane bank-column; Vt stores were 16-way).
// ---------------------------------------------------------------------------

typedef _Float16 f16;
typedef _Float16 v8h __attribute__((ext_vector_type(8)));
typedef float    v4f __attribute__((ext_vector_type(4)));

#define B_   2
#define L_   2048
#define D_   1024
#define H_   16
#define V_   32000
#define M_   (B_ * L_)   // 4096 rows of the activation matrices

__device__ inline void g2l16(const void* g, void* l) {
  // global -> LDS direct DMA, 16B per lane; LDS dest must be wave-uniform.
  __builtin_amdgcn_global_load_lds((const __attribute__((address_space(1))) void*)g,
                                   (__attribute__((address_space(3))) void*)l,
                                   16, 0, 0);
}

// Bijective XCD swizzle (m204 form): consecutive hardware block ids round-robin
// XCDs; remap so each XCD owns a contiguous chunk of logical tiles (B-panel
// then lives in exactly one XCD L2 instead of all 8).
__device__ inline void xcd_swz(int& bx, int& by, int gx, int gy) {
  int nwg  = gx * gy;
  int orig = by * gx + bx;
  int q = nwg >> 3, r = nwg & 7;
  int xcd = orig & 7, local = orig >> 3;
  int swz = (xcd < r ? xcd * (q + 1) : r * (q + 1) + (xcd - r) * q) + local;
  bx = swz % gx;
  by = swz / gx;
}

// ---------------------------------------------------------------------------
// GEMM: C[M,N] = A[M,K] * Bt[N,K]^T + bias  (all f16 in, f32 accumulate)
// EPI 0: out f16; EPI 1: out f32 = resid + v (residual add); EPI 2: out f32.
// M%128==0, N%128==0, K%32==0. 256 threads, 4 waves in 2x2, 64x64 per wave.
// ---------------------------------------------------------------------------
template<int EPI>
__global__ __launch_bounds__(256) void gemm_bt(
    const f16* __restrict__ A, const f16* __restrict__ Bt,
    const float* __restrict__ bias, const float* resid, void* outp,
    int N, int K)
{
  __shared__ alignas(16) f16 As[128 * 32];
  __shared__ alignas(16) f16 Bs[128 * 32];

  int bx = blockIdx.x, by = blockIdx.y;
  xcd_swz(bx, by, (int)gridDim.x, (int)gridDim.y);

  const int tid  = threadIdx.x;
  const int wave = tid >> 6, lane = tid & 63;
  const int quad = lane >> 4, l16 = lane & 15;
  const long tm = (long)bx * 128;
  const long tn = (long)by * 128;
  const int wm = (wave >> 1) * 64, wn = (wave & 1) * 64;

  v4f acc[4][4];
  for (int i = 0; i < 4; ++i)
    for (int j = 0; j < 4; ++j)
      for (int r = 0; r < 4; ++r) acc[i][j][r] = 0.f;

  for (int k0 = 0; k0 < K; k0 += 32) {
    __syncthreads();
    // stage A/B tiles: 512 chunks of 16B each, 2 per thread per matrix
    for (int h = 0; h < 2; ++h) {
      int c = h * 256 + wave * 64 + lane;          // chunk id
      long row = c >> 2;                            // 0..127
      long koff = (long)k0 + (c & 3) * 8;
      g2l16(A  + (tm + row) * K + koff, As + (h * 256 + wave * 64) * 8);
      g2l16(Bt + (tn + row) * K + koff, Bs + (h * 256 + wave * 64) * 8);
    }
    __syncthreads();   // compiler drains vmcnt(0) before barrier

    v8h a[4], b[4];
    for (int i = 0; i < 4; ++i) {
      a[i] = *(const v8h*)(As + (wm + i * 16 + l16) * 32 + quad * 8);
      b[i] = *(const v8h*)(Bs + (wn + i * 16 + l16) * 32 + quad * 8);
    }
    for (int i = 0; i < 4; ++i)
      for (int j = 0; j < 4; ++j)
        acc[i][j] = __builtin_amdgcn_mfma_f32_16x16x32_f16(a[i], b[j], acc[i][j], 0, 0, 0);
  }

  // epilogue: C layout col=lane&15, row=quad*4+reg
  for (int i = 0; i < 4; ++i)
    for (int r = 0; r < 4; ++r) {
      long row = tm + wm + i * 16 + quad * 4 + r;
      for (int j = 0; j < 4; ++j) {
        long col = tn + wn + j * 16 + l16;
        float v = acc[i][j][r] + bias[col];
        long idx = row * (long)N + col;
        if (EPI == 0)      ((f16*)outp)[idx] = (f16)v;
        else if (EPI == 1) ((float*)outp)[idx] = resid[idx] + v;
        else               ((float*)outp)[idx] = v;
      }
    }
}

// ---------------------------------------------------------------------------
// 128x64-tile GEMM for narrow-N (N%64==0). Doubles block count vs 128x128 so
// N=1024 launches 512 blocks (2/CU, 2 waves/SIMD) instead of 256 (1 wave/SIMD).
// 4 waves in 2x2, 64x32 per wave.
// ---------------------------------------------------------------------------
template<int EPI>
__global__ __launch_bounds__(256) void gemm64_bt(
    const f16* __restrict__ A, const f16* __restrict__ Bt,
    const float* __restrict__ bias, const float* resid, void* outp,
    int N, int K)
{
  __shared__ alignas(16) f16 As[128 * 32];
  __shared__ alignas(16) f16 Bs[64 * 32];

  int bx = blockIdx.x, by = blockIdx.y;
  xcd_swz(bx, by, (int)gridDim.x, (int)gridDim.y);

  const int tid  = threadIdx.x;
  const int wave = tid >> 6, lane = tid & 63;
  const int quad = lane >> 4, l16 = lane & 15;
  const long tm = (long)bx * 128;
  const long tn = (long)by * 64;
  const int wm = (wave >> 1) * 64, wn = (wave & 1) * 32;

  v4f acc[4][2];
  for (int i = 0; i < 4; ++i)
    for (int j = 0; j < 2; ++j)
      for (int r = 0; r < 4; ++r) acc[i][j][r] = 0.f;

  for (int k0 = 0; k0 < K; k0 += 32) {
    __syncthreads();
    for (int h = 0; h < 2; ++h) {                  // A: 512 chunks, 2/thread
      int c = h * 256 + wave * 64 + lane;
      long row = c >> 2;
      long koff = (long)k0 + (c & 3) * 8;
      g2l16(A + (tm + row) * K + koff, As + (h * 256 + wave * 64) * 8);
    }
    {                                              // B: 256 chunks, 1/thread
      int c = wave * 64 + lane;
      long row = c >> 2;                           // 0..63
      long koff = (long)k0 + (c & 3) * 8;
      g2l16(Bt + (tn + row) * K + koff, Bs + (wave * 64) * 8);
    }
    __syncthreads();

    v8h a[4], b[2];
    for (int i = 0; i < 4; ++i)
      a[i] = *(const v8h*)(As + (wm + i * 16 + l16) * 32 + quad * 8);
    for (int j = 0; j < 2; ++j)
      b[j] = *(const v8h*)(Bs + (wn + j * 16 + l16) * 32 + quad * 8);
    for (int i = 0; i < 4; ++i)
      for (int j = 0; j < 2; ++j)
        acc[i][j] = __builtin_amdgcn_mfma_f32_16x16x32_f16(a[i], b[j], acc[i][j], 0, 0, 0);
  }

  for (int i = 0; i < 4; ++i)
    for (int r = 0; r < 4; ++r) {
      long row = tm + wm + i * 16 + quad * 4 + r;
      for (int j = 0; j < 2; ++j) {
        long col = tn + wn + j * 16 + l16;
        float v = acc[i][j][r] + bias[col];
        long idx = row * (long)N + col;
        if (EPI == 0)      ((f16*)outp)[idx] = (f16)v;
        else if (EPI == 1) ((float*)outp)[idx] = resid[idx] + v;
        else               ((float*)outp)[idx] = v;
      }
    }
}

// ---------------------------------------------------------------------------
// Flash attention: grid (L/64, B*H), 256 threads. Wave w owns 16 query rows.
// qkv layout: [(b*L+l)][3072] with q|k|v at +0/+1024/+2048, head at h*64.
// LDS XOR swizzles: Ks chunk ^= row&7 (reads were a 16-lane bank column);
// Vt chunk ^= (row>>1)&3 with key-major staging (stores were 16-way).
// ---------------------------------------------------------------------------
__global__ __launch_bounds__(256) void attn_k(const f16* __restrict__ qkv,
                                              f16* __restrict__ attno)
{
  const int qt = (int)gridDim.x - 1 - blockIdx.x;  // heavy causal tiles first
  const int bh = blockIdx.y;
  const int b = bh >> 4, h = bh & 15;
  const int tid = threadIdx.x;
  const int wave = tid >> 6, lane = tid & 63;
  const int quad = lane >> 4, l16 = lane & 15;

  __shared__ alignas(16) f16 Ks[32 * 64];     // [key][dh], chunk-swizzled
  __shared__ alignas(16) f16 Vt[64 * 32];     // [dh][key], chunk-swizzled
  __shared__ alignas(16) f16 Ps[4][16 * 32];  // per-wave P tile [q][key]

  const f16* base = qkv + (size_t)b * L_ * 3072 + h * 64;

  // Q A-frags (dh halves): A[m=lane&15][k=quad*8+j]
  const int qrow = qt * 64 + wave * 16 + l16;
  const v8h qf0 = *(const v8h*)(base + (size_t)qrow * 3072 + quad * 8);
  const v8h qf1 = *(const v8h*)(base + (size_t)qrow * 3072 + 32 + quad * 8);

  v4f of[4];
  float m_i[4], l_i[4];
  for (int n = 0; n < 4; ++n)
    for (int r = 0; r < 4; ++r) of[n][r] = 0.f;
  for (int r = 0; r < 4; ++r) { m_i[r] = -1e30f; l_i[r] = 0.f; }

  const int kr = tid >> 3, kc = tid & 7;     // K staging (coalesced globals)
  const int vkr = tid & 31, vkc = tid >> 5;  // V staging (key-major for LDS)
  const int nblocks = qt * 2 + 2;            // causal bound, uniform in block

  for (int kb = 0; kb < nblocks; ++kb) {
    const int key0 = kb * 32;
    __syncthreads();
    {
      const f16* ksrc = base + 1024 + (size_t)(key0 + kr) * 3072 + kc * 8;
      *(v8h*)(Ks + kr * 64 + ((kc ^ (kr & 7)) * 8)) = *(const v8h*)ksrc;
      const f16* vsrc = base + 2048 + (size_t)(key0 + vkr) * 3072 + vkc * 8;
      v8h vv = *(const v8h*)vsrc;
      const int vc = vkr >> 3, vs = vkr & 7;
      for (int e = 0; e < 8; ++e) {
        int row = vkc * 8 + e;
        Vt[row * 32 + ((vc ^ ((row >> 1) & 3)) * 8) + vs] = vv[e];
      }
    }
    __syncthreads();

    // S = Q K^T for two 16-key sub-blocks
    v4f sf[2];
    for (int s = 0; s < 2; ++s)
      for (int r = 0; r < 4; ++r) sf[s][r] = 0.f;
    for (int s = 0; s < 2; ++s) {
      int row = s * 16 + l16;
      v8h kf0 = *(const v8h*)(Ks + row * 64 + ((quad ^ (row & 7)) * 8));
      v8h kf1 = *(const v8h*)(Ks + row * 64 + (((4 + quad) ^ (row & 7)) * 8));
      sf[s] = __builtin_amdgcn_mfma_f32_16x16x32_f16(qf0, kf0, sf[s], 0, 0, 0);
      sf[s] = __builtin_amdgcn_mfma_f32_16x16x32_f16(qf1, kf1, sf[s], 0, 0, 0);
    }

    const int qg0 = qt * 64 + wave * 16 + quad * 4;
    float pv[2][4];
    for (int s = 0; s < 2; ++s)
      for (int r = 0; r < 4; ++r) {
        float sc = sf[s][r] * 0.125f;              // 1/sqrt(64)
        int kg = key0 + s * 16 + l16;
        if (kg > qg0 + r) sc = -1e30f;             // causal mask
        pv[s][r] = sc;
      }

    for (int r = 0; r < 4; ++r) {
      float mx = fmaxf(pv[0][r], pv[1][r]);
      for (int o = 8; o; o >>= 1) mx = fmaxf(mx, __shfl_xor(mx, o, 64));
      float mnew = fmaxf(m_i[r], mx);
      float alpha = expf(m_i[r] - mnew);
      m_i[r] = mnew;
      pv[0][r] = expf(pv[0][r] - mnew);
      pv[1][r] = expf(pv[1][r] - mnew);
      float rs = pv[0][r] + pv[1][r];
      for (int o = 8; o; o >>= 1) rs += __shfl_xor(rs, o, 64);
      l_i[r] = l_i[r] * alpha + rs;
      for (int n = 0; n < 4; ++n) of[n][r] *= alpha;
      Ps[wave][(quad * 4 + r) * 32 + l16]      = (f16)pv[0][r];
      Ps[wave][(quad * 4 + r) * 32 + 16 + l16] = (f16)pv[1][r];
    }
    __syncthreads();   // P C-layout -> A-layout via LDS (and lgkm drain)

    v8h pf = *(const v8h*)(&Ps[wave][0] + l16 * 32 + quad * 8);
    for (int n = 0; n < 4; ++n) {
      int vrow = n * 16 + l16;
      v8h vf = *(const v8h*)(Vt + vrow * 32 + ((quad ^ ((vrow >> 1) & 3)) * 8));
      of[n] = __builtin_amdgcn_mfma_f32_16x16x32_f16(pf, vf, of[n], 0, 0, 0);
    }
  }

  const int q = qt * 64 + wave * 16 + quad * 4;
  f16* orow = attno + (size_t)b * L_ * 1024 + h * 64;
  for (int r = 0; r < 4; ++r) {
    float inv = 1.0f / l_i[r];
    for (int n = 0; n < 4; ++n)
      orow[(size_t)(q + r) * 1024 + n * 16 + l16] = (f16)(of[n][r] * inv);
  }
}

// ---------------------------------------------------------------------------
// small kernels
// ---------------------------------------------------------------------------
__global__ __launch_bounds__(256) void embed_pe(const int* __restrict__ ids,
                                                const float* __restrict__ emb,
                                                float* __restrict__ x)
{
  const int bl = blockIdx.x;          // 0..4095
  const int l = bl & (L_ - 1);
  const int id = ids[bl];
  const float* e = emb + (size_t)id * D_;
  float* xr = x + (size_t)bl * D_;
  const int d0 = threadIdx.x * 4;
  for (int i = 0; i < 4; ++i) {
    int d = d0 + i;
    int p = d >> 1;
    float ang = (float)l * expf((float)(2 * p) * -0.008994473019508053f); // ln(1e4)/1024
    float pe = (d & 1) ? cosf(ang) : sinf(ang);
    xr[d] = e[d] + pe;
  }
}

__global__ __launch_bounds__(256) void rmsnorm_k(const float* __restrict__ x,
                                                 const float* __restrict__ gamma,
                                                 f16* __restrict__ y)
{
  const int row = blockIdx.x;
  const float4 v = ((const float4*)(x + (size_t)row * D_))[threadIdx.x];
  float s = v.x * v.x + v.y * v.y + v.z * v.z + v.w * v.w;
  for (int o = 32; o; o >>= 1) s += __shfl_xor(s, o, 64);
  __shared__ float red[4];
  const int wave = threadIdx.x >> 6;
  if ((threadIdx.x & 63) == 0) red[wave] = s;
  __syncthreads();
  const float tot = red[0] + red[1] + red[2] + red[3];
  const float scale = rsqrtf(tot * (1.0f / D_) + 1e-6f);
  f16* yr = y + (size_t)row * D_;
  const int d = threadIdx.x * 4;
  yr[d]     = (f16)(v.x * scale * gamma[d]);
  yr[d + 1] = (f16)(v.y * scale * gamma[d + 1]);
  yr[d + 2] = (f16)(v.z * scale * gamma[d + 2]);
  yr[d + 3] = (f16)(v.w * scale * gamma[d + 3]);
}

// f32 [K,N] -> f16 [N,K] (transpose + convert), 32x32 LDS tiles
__global__ __launch_bounds__(256) void transpose_cvt(const float* __restrict__ in,
                                                     f16* __restrict__ out,
                                                     int K, int N)
{
  __shared__ float tile[32][33];
  const int r = threadIdx.x >> 5, c = threadIdx.x & 31;
  const size_t bk = (size_t)blockIdx.y * 32;
  const size_t bn = (size_t)blockIdx.x * 32;
  for (int i = 0; i < 32; i += 8)
    tile[r + i][c] = in[(bk + r + i) * N + bn + c];
  __syncthreads();
  for (int i = 0; i < 32; i += 8)
    out[(bn + r + i) * K + bk + c] = (f16)tile[c][r + i];
}

__global__ __launch_bounds__(256) void gate_k(const f16* __restrict__ PU,
                                              f16* __restrict__ g)
{
  const int e = (blockIdx.x * 256 + threadIdx.x) * 4;
  const int row = e >> 11, col = e & 2047;
  const f16* p = PU + (size_t)row * 4096 + col;
  const f16* u = p + 2048;
  f16* go = g + (size_t)row * 2048 + col;
  for (int i = 0; i < 4; ++i) {
    float z = (float)p[i] * (float)u[i];
    go[i] = (f16)(z / (1.0f + expf(-z)));
  }
}

__global__ __launch_bounds__(256) void cast_k(const float* __restrict__ x,
                                              f16* __restrict__ y)
{
  const int i = blockIdx.x * 1024 + threadIdx.x * 4;
  const float4 v = *(const float4*)(x + i);
  y[i] = (f16)v.x; y[i + 1] = (f16)v.y; y[i + 2] = (f16)v.z; y[i + 3] = (f16)v.w;
}

__global__ __launch_bounds__(256) void build_biases(
    const float* bq, const float* bk, const float* bv,
    const float* bp, const float* bu, float* bqkv, float* bpu)
{
  const int i = blockIdx.x;
  for (int j = threadIdx.x; j < 3072; j += 256)
    bqkv[i * 3072 + j] = j < 1024 ? bq[i * 1024 + j]
                       : j < 2048 ? bk[i * 1024 + j - 1024]
                                  : bv[i * 1024 + j - 2048];
  for (int j = threadIdx.x; j < 4096; j += 256)
    bpu[i * 4096 + j] = j < 2048 ? bp[i * 2048 + j] : bu[i * 2048 + j - 2048];
}

// ---------------------------------------------------------------------------
extern "C" void kernel_launch(void* const* d_in, const int* in_sizes, int n_in,
                              void* d_out, int out_size, void* d_ws, size_t ws_size,
                              hipStream_t stream)
{
  (void)in_sizes; (void)n_in; (void)out_size; (void)ws_size;
  const int*   ids     = (const int*)  d_in[0];
  const float* embed   = (const float*)d_in[1];
  const float* Wq      = (const float*)d_in[2];
  const float* bq      = (const float*)d_in[3];
  const float* Wk      = (const float*)d_in[4];
  const float* bk      = (const float*)d_in[5];
  const float* Wv      = (const float*)d_in[6];
  const float* bv      = (const float*)d_in[7];
  const float* Wo      = (const float*)d_in[8];
  const float* bo      = (const float*)d_in[9];
  const float* Wproj   = (const float*)d_in[10];
  const float* bproj   = (const float*)d_in[11];
  const float* Wup     = (const float*)d_in[12];
  const float* bup     = (const float*)d_in[13];
  const float* Wdown   = (const float*)d_in[14];
  const float* bdown   = (const float*)d_in[15];
  const float* gammas  = (const float*)d_in[16];
  const float* Wlogits = (const float*)d_in[17];
  const float* blogits = (const float*)d_in[18];

  char* ws = (char*)d_ws;
  float* x    = (float*)ws;                       // 16,777,216 B
  f16*   y    = (f16*)  (ws + 16777216);          //  8,388,608 B
  float* bqkv = (float*)(ws + 25165824);          //     49,152 B
  float* bpu  = (float*)(ws + 25214976);          //     65,536 B
  f16*   wbuf = (f16*)  (ws + 25280512);          // 65,536,000 B (WlogitsT max)
  f16* wqkvT  = wbuf;                 // [3072][1024]
  f16* woT    = wbuf + 3145728;       // [1024][1024]
  f16* wpuT   = wbuf + 4194304;       // [4096][1024]
  f16* wdownT = wbuf + 8388608;       // [1024][2048]

  // transient activations live in d_out until the final logits GEMM
  char* ob  = (char*)d_out;
  f16* qkv   = (f16*)ob;               // [4096][3072] 25,165,824 B
  f16* attno = (f16*)(ob + 25165824);  // [4096][1024]  8,388,608 B
  f16* PU    = (f16*)(ob + 33554432);  // [4096][4096] 33,554,432 B
  f16* g     = (f16*)(ob + 67108864);  // [4096][2048] 16,777,216 B

  embed_pe<<<M_, 256, 0, stream>>>(ids, embed, x);
  build_biases<<<4, 256, 0, stream>>>(bq, bk, bv, bproj, bup, bqkv, bpu);

  for (int i = 0; i < 4; ++i) {
    const float* Wqi = Wq + (size_t)i * 1048576;
    const float* Wki = Wk + (size_t)i * 1048576;
    const float* Wvi = Wv + (size_t)i * 1048576;
    const float* Woi = Wo + (size_t)i * 1048576;
    const float* Wpi = Wproj + (size_t)i * 2097152;
    const float* Wui = Wup   + (size_t)i * 2097152;
    const float* Wdi = Wdown + (size_t)i * 2097152;

    transpose_cvt<<<dim3(32, 32), 256, 0, stream>>>(Wqi, wqkvT,                1024, 1024);
    transpose_cvt<<<dim3(32, 32), 256, 0, stream>>>(Wki, wqkvT + 1048576,      1024, 1024);
    transpose_cvt<<<dim3(32, 32), 256, 0, stream>>>(Wvi, wqkvT + 2097152,      1024, 1024);
    transpose_cvt<<<dim3(32, 32), 256, 0, stream>>>(Woi, woT,                  1024, 1024);
    transpose_cvt<<<dim3(64, 32), 256, 0, stream>>>(Wpi, wpuT,                 1024, 2048);
    transpose_cvt<<<dim3(64, 32), 256, 0, stream>>>(Wui, wpuT + 2097152,       1024, 2048);
    transpose_cvt<<<dim3(32, 64), 256, 0, stream>>>(Wdi, wdownT,               2048, 1024);

    rmsnorm_k<<<M_, 256, 0, stream>>>(x, gammas + (size_t)(2 * i) * 1024, y);
    gemm_bt<0><<<dim3(32, 24), 256, 0, stream>>>(y, wqkvT, bqkv + i * 3072, nullptr, qkv, 3072, 1024);
    attn_k<<<dim3(32, 32), 256, 0, stream>>>(qkv, attno);
    gemm64_bt<1><<<dim3(32, 16), 256, 0, stream>>>(attno, woT, bo + i * 1024, x, x, 1024, 1024);

    rmsnorm_k<<<M_, 256, 0, stream>>>(x, gammas + (size_t)(2 * i + 1) * 1024, y);
    gemm_bt<0><<<dim3(32, 32), 256, 0, stream>>>(y, wpuT, bpu + i * 4096, nullptr, PU, 4096, 1024);
    gate_k<<<8192, 256, 0, stream>>>(PU, g);
    gemm64_bt<1><<<dim3(32, 16), 256, 0, stream>>>(g, wdownT, bdown + i * 1024, x, x, 1024, 2048);
  }

  transpose_cvt<<<dim3(1000, 32), 256, 0, stream>>>(Wlogits, wbuf, 1024, 32000);
  cast_k<<<M_, 256, 0, stream>>>(x, y);
  gemm_bt<2><<<dim3(32, 250), 256, 0, stream>>>(y, wbuf, blogits, nullptr, (float*)d_out, 32000, 1024);
}

// Round 2
// 2527.205 us; speedup vs baseline: 1.1850x; 1.0904x over previous
//
#include <hip/hip_runtime.h>

// ---------------------------------------------------------------------------
// Decoder fwd: B=2, L=2048, D=1024, H=16 (dh=64), V=32000, N_LAYER=4, FFN=2D.
// f16 MFMA everywhere; residual stream kept f32 in ws.
// R2: gemm_wt 256x128 tile (wave tile 128x64 -> 42.7 FLOP/LDS-byte, lifts the
//     LDS-BW util cap 41%->54%), LDS chunk swizzle jslot^((row>>1)&3) on all
//     GEMM tiles (kills half-wave bank imbalance, 32.8M conflicts), grouped
//     XCD ordering (A band 2MB stays in L2), attn KVBLK=64 with full swizzles.
// ---------------------------------------------------------------------------

typedef _Float16 f16;
typedef _Float16 v8h __attribute__((ext_vector_type(8)));
typedef float    v4f __attribute__((ext_vector_type(4)));

#define B_   2
#define L_   2048
#define D_   1024
#define H_   16
#define V_   32000
#define M_   (B_ * L_)   // 4096 rows of the activation matrices

__device__ inline void g2l16(const void* g, void* l) {
  // global -> LDS direct DMA, 16B per lane; LDS dest must be wave-uniform.
  __builtin_amdgcn_global_load_lds((const __attribute__((address_space(1))) void*)g,
                                   (__attribute__((address_space(3))) void*)l,
                                   16, 0, 0);
}

// XCD-chunked + grouped tile order: per XCD a contiguous chunk of logical ids;
// logical order = bands of MG m-tiles, n-major inside a band (A-band ~2MB stays
// in L2 while B streams). Requires GX % MG == 0, grid = (GX, GY).
__device__ inline void tile_map(int& m, int& n) {
  const int GX = (int)gridDim.x, GY = (int)gridDim.y;
  const int nwg = GX * GY;
  const int flat = (int)(blockIdx.y * gridDim.x + blockIdx.x);
  const int per = nwg >> 3, r = nwg & 7;
  const int xcd = flat & 7, lo = flat >> 3;
  const int swz = (xcd < r ? xcd * (per + 1) : r * (per + 1) + (xcd - r) * per) + lo;
  const int MG = 4;
  const int band = swz / (MG * GY), rem = swz % (MG * GY);
  n = rem / MG;
  m = band * MG + (rem % MG);
}

// ---------------------------------------------------------------------------
// GEMM: C[M,N] = A[M,K] * Bt[N,K]^T + bias  (f16 in, f32 accumulate)
// 256x128 tile, 256 threads, 4 waves 2x2, each wave owns 128x64.
// LDS chunk swizzle: slot j' at row holds global k-chunk j' ^ ((row>>1)&3).
// EPI 0: out f16; EPI 1: out f32 = resid + v; EPI 2: out f32.
// ---------------------------------------------------------------------------
template<int EPI>
__global__ __launch_bounds__(256, 2) void gemm_wt(
    const f16* __restrict__ A, const f16* __restrict__ Bt,
    const float* __restrict__ bias, const float* resid, void* outp,
    int N, int K)
{
  __shared__ alignas(16) f16 As[256 * 32];
  __shared__ alignas(16) f16 Bs[128 * 32];

  int bm, bn;
  tile_map(bm, bn);

  const int tid  = threadIdx.x;
  const int wave = tid >> 6, lane = tid & 63;
  const int quad = lane >> 4, l16 = lane & 15;
  const long tm = (long)bm * 256;
  const long tn = (long)bn * 128;
  const int wm = (wave >> 1) * 128, wn = (wave & 1) * 64;

  v4f acc[8][4];
  for (int i = 0; i < 8; ++i)
    for (int j = 0; j < 4; ++j)
      for (int r = 0; r < 4; ++r) acc[i][j][r] = 0.f;

  for (int k0 = 0; k0 < K; k0 += 32) {
    __syncthreads();
    // A: 1024 chunks of 16B (256 rows x 4 slots), 4 per thread
    for (int h = 0; h < 4; ++h) {
      int c = h * 256 + tid;
      long row = c >> 2;
      int jslot = c & 3;
      long koff = (long)k0 + ((jslot ^ ((row >> 1) & 3)) << 3);
      g2l16(A + (tm + row) * K + koff, As + (h * 256 + wave * 64) * 8);
    }
    // B: 512 chunks (128 rows x 4 slots), 2 per thread
    for (int h = 0; h < 2; ++h) {
      int c = h * 256 + tid;
      long row = c >> 2;
      int jslot = c & 3;
      long koff = (long)k0 + ((jslot ^ ((row >> 1) & 3)) << 3);
      g2l16(Bt + (tn + row) * K + koff, Bs + (h * 256 + wave * 64) * 8);
    }
    __syncthreads();   // compiler drains vmcnt(0) before barrier

    v8h a[8], b[4];
    for (int i = 0; i < 8; ++i) {
      int arow = wm + i * 16 + l16;
      a[i] = *(const v8h*)(As + arow * 32 + ((quad ^ ((arow >> 1) & 3)) << 3));
    }
    for (int j = 0; j < 4; ++j) {
      int brow = wn + j * 16 + l16;
      b[j] = *(const v8h*)(Bs + brow * 32 + ((quad ^ ((brow >> 1) & 3)) << 3));
    }
    for (int i = 0; i < 8; ++i)
      for (int j = 0; j < 4; ++j)
        acc[i][j] = __builtin_amdgcn_mfma_f32_16x16x32_f16(a[i], b[j], acc[i][j], 0, 0, 0);
  }

  // epilogue: C layout col=lane&15, row=quad*4+reg
  for (int i = 0; i < 8; ++i)
    for (int r = 0; r < 4; ++r) {
      long row = tm + wm + i * 16 + quad * 4 + r;
      for (int j = 0; j < 4; ++j) {
        long col = tn + wn + j * 16 + l16;
        float v = acc[i][j][r] + bias[col];
        long idx = row * (long)N + col;
        if (EPI == 0)      ((f16*)outp)[idx] = (f16)v;
        else if (EPI == 1) ((float*)outp)[idx] = resid[idx] + v;
        else               ((float*)outp)[idx] = v;
      }
    }
}

// ---------------------------------------------------------------------------
// 128x64-tile GEMM for narrow-N (N=1024): 512 blocks, 2 blocks/CU.
// Same LDS chunk swizzle as gemm_wt.
// ---------------------------------------------------------------------------
template<int EPI>
__global__ __launch_bounds__(256) void gemm64_bt(
    const f16* __restrict__ A, const f16* __restrict__ Bt,
    const float* __restrict__ bias, const float* resid, void* outp,
    int N, int K)
{
  __shared__ alignas(16) f16 As[128 * 32];
  __shared__ alignas(16) f16 Bs[64 * 32];

  int bm, bn;
  tile_map(bm, bn);

  const int tid  = threadIdx.x;
  const int wave = tid >> 6, lane = tid & 63;
  const int quad = lane >> 4, l16 = lane & 15;
  const long tm = (long)bm * 128;
  const long tn = (long)bn * 64;
  const int wm = (wave >> 1) * 64, wn = (wave & 1) * 32;

  v4f acc[4][2];
  for (int i = 0; i < 4; ++i)
    for (int j = 0; j < 2; ++j)
      for (int r = 0; r < 4; ++r) acc[i][j][r] = 0.f;

  for (int k0 = 0; k0 < K; k0 += 32) {
    __syncthreads();
    for (int h = 0; h < 2; ++h) {                  // A: 512 chunks, 2/thread
      int c = h * 256 + tid;
      long row = c >> 2;
      int jslot = c & 3;
      long koff = (long)k0 + ((jslot ^ ((row >> 1) & 3)) << 3);
      g2l16(A + (tm + row) * K + koff, As + (h * 256 + wave * 64) * 8);
    }
    {                                              // B: 256 chunks, 1/thread
      int c = tid;
      long row = c >> 2;                           // 0..63
      int jslot = c & 3;
      long koff = (long)k0 + ((jslot ^ ((row >> 1) & 3)) << 3);
      g2l16(Bt + (tn + row) * K + koff, Bs + (wave * 64) * 8);
    }
    __syncthreads();

    v8h a[4], b[2];
    for (int i = 0; i < 4; ++i) {
      int arow = wm + i * 16 + l16;
      a[i] = *(const v8h*)(As + arow * 32 + ((quad ^ ((arow >> 1) & 3)) << 3));
    }
    for (int j = 0; j < 2; ++j) {
      int brow = wn + j * 16 + l16;
      b[j] = *(const v8h*)(Bs + brow * 32 + ((quad ^ ((brow >> 1) & 3)) << 3));
    }
    for (int i = 0; i < 4; ++i)
      for (int j = 0; j < 2; ++j)
        acc[i][j] = __builtin_amdgcn_mfma_f32_16x16x32_f16(a[i], b[j], acc[i][j], 0, 0, 0);
  }

  for (int i = 0; i < 4; ++i)
    for (int r = 0; r < 4; ++r) {
      long row = tm + wm + i * 16 + quad * 4 + r;
      for (int j = 0; j < 2; ++j) {
        long col = tn + wn + j * 16 + l16;
        float v = acc[i][j][r] + bias[col];
        long idx = row * (long)N + col;
        if (EPI == 0)      ((f16*)outp)[idx] = (f16)v;
        else if (EPI == 1) ((float*)outp)[idx] = resid[idx] + v;
        else               ((float*)outp)[idx] = v;
      }
    }
}

// ---------------------------------------------------------------------------
// Flash attention: grid (L/64, B*H), 256 threads, KVBLK=64 (halves the
// softmax/barrier iterations). Wave w owns 16 query rows.
// All LDS tiles XOR-swizzled: slot-chunk c' at row holds global chunk
// c' ^ (row & 7)  (rows are 128B -> 8 chunks of 16B).
// ---------------------------------------------------------------------------
__global__ __launch_bounds__(256) void attn_k(const f16* __restrict__ qkv,
                                              f16* __restrict__ attno)
{
  const int qt = (int)gridDim.x - 1 - blockIdx.x;  // heavy causal tiles first
  const int bh = blockIdx.y;
  const int b = bh >> 4, h = bh & 15;
  const int tid = threadIdx.x;
  const int wave = tid >> 6, lane = tid & 63;
  const int quad = lane >> 4, l16 = lane & 15;

  __shared__ alignas(16) f16 Ks[64 * 64];     // [key][dh], chunk-swizzled
  __shared__ alignas(16) f16 Vt[64 * 64];     // [dh][key], chunk-swizzled
  __shared__ alignas(16) f16 Ps[4][16 * 64];  // per-wave P [q][key], swizzled

  const f16* base = qkv + (size_t)b * L_ * 3072 + h * 64;

  // Q A-frags (dh halves): A[m=lane&15][k=quad*8+j]
  const int qrow = qt * 64 + wave * 16 + l16;
  const v8h qf0 = *(const v8h*)(base + (size_t)qrow * 3072 + quad * 8);
  const v8h qf1 = *(const v8h*)(base + (size_t)qrow * 3072 + 32 + quad * 8);

  v4f of[4];
  float m_i[4], l_i[4];
  for (int n = 0; n < 4; ++n)
    for (int r = 0; r < 4; ++r) of[n][r] = 0.f;
  for (int r = 0; r < 4; ++r) { m_i[r] = -1e30f; l_i[r] = 0.f; }

  const int nblocks = qt + 1;                 // causal bound, uniform in block

  for (int kb = 0; kb < nblocks; ++kb) {
    const int key0 = kb * 64;
    __syncthreads();
    // K: 64 rows x 8 chunks = 512 chunks, 2/thread via global_load_lds.
    for (int h2 = 0; h2 < 2; ++h2) {
      int c = h2 * 256 + tid;
      int row = c >> 3, jslot = c & 7;
      const f16* ksrc = base + 1024 + (size_t)(key0 + row) * 3072
                        + ((jslot ^ (row & 7)) << 3);
      g2l16(ksrc, Ks + (h2 * 256 + wave * 64) * 8);
    }
    // V: reg-staged transpose into Vt[d][key], swizzled stores.
    for (int h2 = 0; h2 < 2; ++h2) {
      int key = tid >> 2;
      int dc = (tid & 3) + h2 * 4;
      const f16* vsrc = base + 2048 + (size_t)(key0 + key) * 3072 + dc * 8;
      v8h vv = *(const v8h*)vsrc;
      for (int e = 0; e < 8; ++e) {
        int d = dc * 8 + e;
        Vt[d * 64 + (((key >> 3) ^ (d & 7)) << 3) + (key & 7)] = vv[e];
      }
    }
    __syncthreads();

    // S = Q K^T for four 16-key sub-blocks
    v4f sf[4];
    for (int s = 0; s < 4; ++s)
      for (int r = 0; r < 4; ++r) sf[s][r] = 0.f;
    for (int s = 0; s < 4; ++s) {
      int krow = s * 16 + l16;
      v8h kf0 = *(const v8h*)(Ks + krow * 64 + ((quad       ^ (krow & 7)) << 3));
      v8h kf1 = *(const v8h*)(Ks + krow * 64 + (((4 + quad) ^ (krow & 7)) << 3));
      sf[s] = __builtin_amdgcn_mfma_f32_16x16x32_f16(qf0, kf0, sf[s], 0, 0, 0);
      sf[s] = __builtin_amdgcn_mfma_f32_16x16x32_f16(qf1, kf1, sf[s], 0, 0, 0);
    }

    const int qg0 = qt * 64 + wave * 16 + quad * 4;
    float pv[4][4];
    for (int s = 0; s < 4; ++s)
      for (int r = 0; r < 4; ++r) {
        float sc = sf[s][r] * 0.125f;              // 1/sqrt(64)
        int kg = key0 + s * 16 + l16;
        if (kg > qg0 + r) sc = -1e30f;             // causal mask
        pv[s][r] = sc;
      }

    for (int r = 0; r < 4; ++r) {
      float mx = fmaxf(fmaxf(pv[0][r], pv[1][r]), fmaxf(pv[2][r], pv[3][r]));
      for (int o = 8; o; o >>= 1) mx = fmaxf(mx, __shfl_xor(mx, o, 64));
      float mnew = fmaxf(m_i[r], mx);
      float alpha = expf(m_i[r] - mnew);
      m_i[r] = mnew;
      float rs = 0.f;
      for (int s = 0; s < 4; ++s) {
        pv[s][r] = expf(pv[s][r] - mnew);
        rs += pv[s][r];
      }
      for (int o = 8; o; o >>= 1) rs += __shfl_xor(rs, o, 64);
      l_i[r] = l_i[r] * alpha + rs;
      for (int n = 0; n < 4; ++n) of[n][r] *= alpha;
      int qr = quad * 4 + r;
      for (int s = 0; s < 4; ++s) {
        int key = s * 16 + l16;
        Ps[wave][qr * 64 + ((((key >> 3)) ^ (qr & 7)) << 3) + (key & 7)]
            = (f16)pv[s][r];
      }
    }
    __syncthreads();   // P C-layout -> A-layout via LDS (and lgkm drain)

    v8h pf0 = *(const v8h*)(&Ps[wave][0] + l16 * 64 + ((quad       ^ (l16 & 7)) << 3));
    v8h pf1 = *(const v8h*)(&Ps[wave][0] + l16 * 64 + (((4 + quad) ^ (l16 & 7)) << 3));
    for (int n = 0; n < 4; ++n) {
      int d = n * 16 + l16;
      v8h vf0 = *(const v8h*)(Vt + d * 64 + ((quad       ^ (d & 7)) << 3));
      v8h vf1 = *(const v8h*)(Vt + d * 64 + (((4 + quad) ^ (d & 7)) << 3));
      of[n] = __builtin_amdgcn_mfma_f32_16x16x32_f16(pf0, vf0, of[n], 0, 0, 0);
      of[n] = __builtin_amdgcn_mfma_f32_16x16x32_f16(pf1, vf1, of[n], 0, 0, 0);
    }
  }

  const int q = qt * 64 + wave * 16 + quad * 4;
  f16* orow = attno + (size_t)b * L_ * 1024 + h * 64;
  for (int r = 0; r < 4; ++r) {
    float inv = 1.0f / l_i[r];
    for (int n = 0; n < 4; ++n)
      orow[(size_t)(q + r) * 1024 + n * 16 + l16] = (f16)(of[n][r] * inv);
  }
}

// ---------------------------------------------------------------------------
// small kernels
// ---------------------------------------------------------------------------
__global__ __launch_bounds__(256) void embed_pe(const int* __restrict__ ids,
                                                const float* __restrict__ emb,
                                                float* __restrict__ x)
{
  const int bl = blockIdx.x;          // 0..4095
  const int l = bl & (L_ - 1);
  const int id = ids[bl];
  const float* e = emb + (size_t)id * D_;
  float* xr = x + (size_t)bl * D_;
  const int d0 = threadIdx.x * 4;
  for (int i = 0; i < 4; ++i) {
    int d = d0 + i;
    int p = d >> 1;
    float ang = (float)l * expf((float)(2 * p) * -0.008994473019508053f); // ln(1e4)/1024
    float pe = (d & 1) ? cosf(ang) : sinf(ang);
    xr[d] = e[d] + pe;
  }
}

__global__ __launch_bounds__(256) void rmsnorm_k(const float* __restrict__ x,
                                                 const float* __restrict__ gamma,
                                                 f16* __restrict__ y)
{
  const int row = blockIdx.x;
  const float4 v = ((const float4*)(x + (size_t)row * D_))[threadIdx.x];
  float s = v.x * v.x + v.y * v.y + v.z * v.z + v.w * v.w;
  for (int o = 32; o; o >>= 1) s += __shfl_xor(s, o, 64);
  __shared__ float red[4];
  const int wave = threadIdx.x >> 6;
  if ((threadIdx.x & 63) == 0) red[wave] = s;
  __syncthreads();
  const float tot = red[0] + red[1] + red[2] + red[3];
  const float scale = rsqrtf(tot * (1.0f / D_) + 1e-6f);
  f16* yr = y + (size_t)row * D_;
  const int d = threadIdx.x * 4;
  yr[d]     = (f16)(v.x * scale * gamma[d]);
  yr[d + 1] = (f16)(v.y * scale * gamma[d + 1]);
  yr[d + 2] = (f16)(v.z * scale * gamma[d + 2]);
  yr[d + 3] = (f16)(v.w * scale * gamma[d + 3]);
}

// f32 [K,N] -> f16 [N,K] (transpose + convert), 32x32 LDS tiles
__global__ __launch_bounds__(256) void transpose_cvt(const float* __restrict__ in,
                                                     f16* __restrict__ out,
                                                     int K, int N)
{
  __shared__ float tile[32][33];
  const int r = threadIdx.x >> 5, c = threadIdx.x & 31;
  const size_t bk = (size_t)blockIdx.y * 32;
  const size_t bn = (size_t)blockIdx.x * 32;
  for (int i = 0; i < 32; i += 8)
    tile[r + i][c] = in[(bk + r + i) * N + bn + c];
  __syncthreads();
  for (int i = 0; i < 32; i += 8)
    out[(bn + r + i) * K + bk + c] = (f16)tile[c][r + i];
}

__global__ __launch_bounds__(256) void gate_k(const f16* __restrict__ PU,
                                              f16* __restrict__ g)
{
  const int e = (blockIdx.x * 256 + threadIdx.x) * 4;
  const int row = e >> 11, col = e & 2047;
  const f16* p = PU + (size_t)row * 4096 + col;
  const f16* u = p + 2048;
  f16* go = g + (size_t)row * 2048 + col;
  for (int i = 0; i < 4; ++i) {
    float z = (float)p[i] * (float)u[i];
    go[i] = (f16)(z / (1.0f + expf(-z)));
  }
}

__global__ __launch_bounds__(256) void cast_k(const float* __restrict__ x,
                                              f16* __restrict__ y)
{
  const int i = blockIdx.x * 1024 + threadIdx.x * 4;
  const float4 v = *(const float4*)(x + i);
  y[i] = (f16)v.x; y[i + 1] = (f16)v.y; y[i + 2] = (f16)v.z; y[i + 3] = (f16)v.w;
}

__global__ __launch_bounds__(256) void build_biases(
    const float* bq, const float* bk, const float* bv,
    const float* bp, const float* bu, float* bqkv, float* bpu)
{
  const int i = blockIdx.x;
  for (int j = threadIdx.x; j < 3072; j += 256)
    bqkv[i * 3072 + j] = j < 1024 ? bq[i * 1024 + j]
                       : j < 2048 ? bk[i * 1024 + j - 1024]
                                  : bv[i * 1024 + j - 2048];
  for (int j = threadIdx.x; j < 4096; j += 256)
    bpu[i * 4096 + j] = j < 2048 ? bp[i * 2048 + j] : bu[i * 2048 + j - 2048];
}

// ---------------------------------------------------------------------------
extern "C" void kernel_launch(void* const* d_in, const int* in_sizes, int n_in,
                              void* d_out, int out_size, void* d_ws, size_t ws_size,
                              hipStream_t stream)
{
  (void)in_sizes; (void)n_in; (void)out_size; (void)ws_size;
  const int*   ids     = (const int*)  d_in[0];
  const float* embed   = (const float*)d_in[1];
  const float* Wq      = (const float*)d_in[2];
  const float* bq      = (const float*)d_in[3];
  const float* Wk      = (const float*)d_in[4];
  const float* bk      = (const float*)d_in[5];
  const float* Wv      = (const float*)d_in[6];
  const float* bv      = (const float*)d_in[7];
  const float* Wo      = (const float*)d_in[8];
  const float* bo      = (const float*)d_in[9];
  const float* Wproj   = (const float*)d_in[10];
  const float* bproj   = (const float*)d_in[11];
  const float* Wup     = (const float*)d_in[12];
  const float* bup     = (const float*)d_in[13];
  const float* Wdown   = (const float*)d_in[14];
  const float* bdown   = (const float*)d_in[15];
  const float* gammas  = (const float*)d_in[16];
  const float* Wlogits = (const float*)d_in[17];
  const float* blogits = (const float*)d_in[18];

  char* ws = (char*)d_ws;
  float* x    = (float*)ws;                       // 16,777,216 B
  f16*   y    = (f16*)  (ws + 16777216);          //  8,388,608 B
  float* bqkv = (float*)(ws + 25165824);          //     49,152 B
  float* bpu  = (float*)(ws + 25214976);          //     65,536 B
  f16*   wbuf = (f16*)  (ws + 25280512);          // 65,536,000 B (WlogitsT max)
  f16* wqkvT  = wbuf;                 // [3072][1024]
  f16* woT    = wbuf + 3145728;       // [1024][1024]
  f16* wpuT   = wbuf + 4194304;       // [4096][1024]
  f16* wdownT = wbuf + 8388608;       // [1024][2048]

  // transient activations live in d_out until the final logits GEMM
  char* ob  = (char*)d_out;
  f16* qkv   = (f16*)ob;               // [4096][3072] 25,165,824 B
  f16* attno = (f16*)(ob + 25165824);  // [4096][1024]  8,388,608 B
  f16* PU    = (f16*)(ob + 33554432);  // [4096][4096] 33,554,432 B
  f16* g     = (f16*)(ob + 67108864);  // [4096][2048] 16,777,216 B

  embed_pe<<<M_, 256, 0, stream>>>(ids, embed, x);
  build_biases<<<4, 256, 0, stream>>>(bq, bk, bv, bproj, bup, bqkv, bpu);

  for (int i = 0; i < 4; ++i) {
    const float* Wqi = Wq + (size_t)i * 1048576;
    const float* Wki = Wk + (size_t)i * 1048576;
    const float* Wvi = Wv + (size_t)i * 1048576;
    const float* Woi = Wo + (size_t)i * 1048576;
    const float* Wpi = Wproj + (size_t)i * 2097152;
    const float* Wui = Wup   + (size_t)i * 2097152;
    const float* Wdi = Wdown + (size_t)i * 2097152;

    transpose_cvt<<<dim3(32, 32), 256, 0, stream>>>(Wqi, wqkvT,                1024, 1024);
    transpose_cvt<<<dim3(32, 32), 256, 0, stream>>>(Wki, wqkvT + 1048576,      1024, 1024);
    transpose_cvt<<<dim3(32, 32), 256, 0, stream>>>(Wvi, wqkvT + 2097152,      1024, 1024);
    transpose_cvt<<<dim3(32, 32), 256, 0, stream>>>(Woi, woT,                  1024, 1024);
    transpose_cvt<<<dim3(64, 32), 256, 0, stream>>>(Wpi, wpuT,                 1024, 2048);
    transpose_cvt<<<dim3(64, 32), 256, 0, stream>>>(Wui, wpuT + 2097152,       1024, 2048);
    transpose_cvt<<<dim3(32, 64), 256, 0, stream>>>(Wdi, wdownT,               2048, 1024);

    rmsnorm_k<<<M_, 256, 0, stream>>>(x, gammas + (size_t)(2 * i) * 1024, y);
    gemm_wt<0><<<dim3(16, 24), 256, 0, stream>>>(y, wqkvT, bqkv + i * 3072, nullptr, qkv, 3072, 1024);
    attn_k<<<dim3(32, 32), 256, 0, stream>>>(qkv, attno);
    gemm64_bt<1><<<dim3(32, 16), 256, 0, stream>>>(attno, woT, bo + i * 1024, x, x, 1024, 1024);

    rmsnorm_k<<<M_, 256, 0, stream>>>(x, gammas + (size_t)(2 * i + 1) * 1024, y);
    gemm_wt<0><<<dim3(16, 32), 256, 0, stream>>>(y, wpuT, bpu + i * 4096, nullptr, PU, 4096, 1024);
    gate_k<<<8192, 256, 0, stream>>>(PU, g);
    gemm64_bt<1><<<dim3(32, 16), 256, 0, stream>>>(g, wdownT, bdown + i * 1024, x, x, 1024, 2048);
  }

  transpose_cvt<<<dim3(1000, 32), 256, 0, stream>>>(Wlogits, wbuf, 1024, 32000);
  cast_k<<<M_, 256, 0, stream>>>(x, y);
  gemm_wt<2><<<dim3(16, 250), 256, 0, stream>>>(y, wbuf, blogits, nullptr, (float*)d_out, 32000, 1024);
}

// Round 3
// 2499.550 us; speedup vs baseline: 1.1981x; 1.0111x over previous
//
#include <hip/hip_runtime.h>

// ---------------------------------------------------------------------------
// Decoder fwd: B=2, L=2048, D=1024, H=16 (dh=64), V=32000, N_LAYER=4, FFN=2D.
// f16 MFMA everywhere; residual stream kept f32 in ws.
// R3: GEMMs now double-buffered depth-2 pipelines with counted vmcnt + raw
//     s_barrier (T3/T4 minimum form): stage tile t+2 while computing tile t,
//     wait vmcnt(6)/(3) instead of the structural vmcnt(0) drain that exposed
//     full load latency every K-step at 2 waves/SIMD occupancy (acc AGPRs eat
//     the unified regfile). +setprio around MFMA cluster (T5).
// ---------------------------------------------------------------------------

typedef _Float16 f16;
typedef _Float16 v8h __attribute__((ext_vector_type(8)));
typedef float    v4f __attribute__((ext_vector_type(4)));

#define B_   2
#define L_   2048
#define D_   1024
#define H_   16
#define V_   32000
#define M_   (B_ * L_)   // 4096 rows of the activation matrices

__device__ inline void g2l16(const void* g, void* l) {
  // global -> LDS direct DMA, 16B per lane; LDS dest must be wave-uniform.
  __builtin_amdgcn_global_load_lds((const __attribute__((address_space(1))) void*)g,
                                   (__attribute__((address_space(3))) void*)l,
                                   16, 0, 0);
}

// XCD-chunked + grouped tile order: per XCD a contiguous chunk of logical ids;
// logical order = bands of MG m-tiles, n-major inside a band (A-band ~2MB stays
// in L2 while B streams). Requires GX % MG == 0, grid = (GX, GY).
__device__ inline void tile_map(int& m, int& n) {
  const int GX = (int)gridDim.x, GY = (int)gridDim.y;
  const int nwg = GX * GY;
  const int flat = (int)(blockIdx.y * gridDim.x + blockIdx.x);
  const int per = nwg >> 3, r = nwg & 7;
  const int xcd = flat & 7, lo = flat >> 3;
  const int swz = (xcd < r ? xcd * (per + 1) : r * (per + 1) + (xcd - r) * per) + lo;
  const int MG = 4;
  const int band = swz / (MG * GY), rem = swz % (MG * GY);
  n = rem / MG;
  m = band * MG + (rem % MG);
}

// ---------------------------------------------------------------------------
// GEMM: C[M,N] = A[M,K] * Bt[N,K]^T + bias  (f16 in, f32 accumulate)
// 256x128 tile, 256 threads, 4 waves 2x2, each wave owns 128x64.
// Double-buffered LDS, depth-2 prefetch, counted vmcnt(6), raw barriers.
// LDS chunk swizzle: slot j' at row holds global k-chunk j' ^ ((row>>1)&3).
// EPI 0: out f16; EPI 1: out f32 = resid + v; EPI 2: out f32.
// ---------------------------------------------------------------------------
template<int EPI>
__global__ __launch_bounds__(256, 2) void gemm_wt(
    const f16* __restrict__ A, const f16* __restrict__ Bt,
    const float* __restrict__ bias, const float* resid, void* outp,
    int N, int K)
{
  __shared__ alignas(16) f16 As[2][256 * 32];
  __shared__ alignas(16) f16 Bs[2][128 * 32];

  int bm, bn;
  tile_map(bm, bn);

  const int tid  = threadIdx.x;
  const int wave = tid >> 6, lane = tid & 63;
  const int quad = lane >> 4, l16 = lane & 15;
  const long tm = (long)bm * 256;
  const long tn = (long)bn * 128;
  const int wm = (wave >> 1) * 128, wn = (wave & 1) * 64;

  // per-thread staging sources (advance 32 f16 per K-tile); swizzle folded in
  const f16* asrc[4];
  const f16* bsrc[2];
  #pragma unroll
  for (int h = 0; h < 4; ++h) {
    int c = h * 256 + tid;
    long row = c >> 2;
    int jslot = c & 3;
    asrc[h] = A + (tm + row) * K + ((jslot ^ ((row >> 1) & 3)) << 3);
  }
  #pragma unroll
  for (int h = 0; h < 2; ++h) {
    int c = h * 256 + tid;
    long row = c >> 2;
    int jslot = c & 3;
    bsrc[h] = Bt + (tn + row) * K + ((jslot ^ ((row >> 1) & 3)) << 3);
  }
  // LDS fragment-read offsets (swizzled), hoisted
  int aoff[8], boff[4];
  #pragma unroll
  for (int i = 0; i < 8; ++i) {
    int arow = wm + i * 16 + l16;
    aoff[i] = arow * 32 + ((quad ^ ((arow >> 1) & 3)) << 3);
  }
  #pragma unroll
  for (int j = 0; j < 4; ++j) {
    int brow = wn + j * 16 + l16;
    boff[j] = brow * 32 + ((quad ^ ((brow >> 1) & 3)) << 3);
  }

  v4f acc[8][4];
  #pragma unroll
  for (int i = 0; i < 8; ++i)
    #pragma unroll
    for (int j = 0; j < 4; ++j)
      #pragma unroll
      for (int r = 0; r < 4; ++r) acc[i][j][r] = 0.f;

  const int nt = K >> 5;

#define STAGE_WT(buf, t)                                                   \
  {                                                                        \
    const long ko_ = (long)(t) << 5;                                       \
    _Pragma("unroll")                                                      \
    for (int h_ = 0; h_ < 4; ++h_)                                         \
      g2l16(asrc[h_] + ko_, As[buf] + (h_ * 256 + wave * 64) * 8);         \
    _Pragma("unroll")                                                      \
    for (int h_ = 0; h_ < 2; ++h_)                                         \
      g2l16(bsrc[h_] + ko_, Bs[buf] + (h_ * 256 + wave * 64) * 8);         \
  }

  STAGE_WT(0, 0)
  STAGE_WT(1, 1)
  asm volatile("s_waitcnt vmcnt(6)" ::: "memory");   // buf0 (own shares) done
  __builtin_amdgcn_s_barrier();                       // buf0 globally ready

  int cur = 0;
  for (int t = 0; t < nt; ++t) {
    v8h a[8], b[4];
    #pragma unroll
    for (int i = 0; i < 8; ++i) a[i] = *(const v8h*)(As[cur] + aoff[i]);
    #pragma unroll
    for (int j = 0; j < 4; ++j) b[j] = *(const v8h*)(Bs[cur] + boff[j]);
    __builtin_amdgcn_s_setprio(1);
    #pragma unroll
    for (int i = 0; i < 8; ++i)
      #pragma unroll
      for (int j = 0; j < 4; ++j)
        acc[i][j] = __builtin_amdgcn_mfma_f32_16x16x32_f16(a[i], b[j], acc[i][j], 0, 0, 0);
    __builtin_amdgcn_s_setprio(0);
    __builtin_amdgcn_sched_barrier(0);
    __builtin_amdgcn_s_barrier();            // all waves done reading buf[cur]
    if (t + 2 < nt) {
      STAGE_WT(cur, t + 2)                   // overwrite buf[cur] with tile t+2
      asm volatile("s_waitcnt vmcnt(6)" ::: "memory");  // tile t+1 loads done
    } else {
      asm volatile("s_waitcnt vmcnt(0)" ::: "memory");
    }
    __builtin_amdgcn_sched_barrier(0);
    __builtin_amdgcn_s_barrier();            // buf[1-cur] staged & visible
    cur ^= 1;
  }

  // epilogue: C layout col=lane&15, row=quad*4+reg
  #pragma unroll
  for (int i = 0; i < 8; ++i)
    #pragma unroll
    for (int r = 0; r < 4; ++r) {
      long row = tm + wm + i * 16 + quad * 4 + r;
      #pragma unroll
      for (int j = 0; j < 4; ++j) {
        long col = tn + wn + j * 16 + l16;
        float v = acc[i][j][r] + bias[col];
        long idx = row * (long)N + col;
        if (EPI == 0)      ((f16*)outp)[idx] = (f16)v;
        else if (EPI == 1) ((float*)outp)[idx] = resid[idx] + v;
        else               ((float*)outp)[idx] = v;
      }
    }
#undef STAGE_WT
}

// ---------------------------------------------------------------------------
// 128x64-tile GEMM for narrow-N (N=1024): 512 blocks, 2+ blocks/CU.
// Same pipelined structure; 3 loads/thread/tile -> vmcnt(3).
// ---------------------------------------------------------------------------
template<int EPI>
__global__ __launch_bounds__(256) void gemm64_bt(
    const f16* __restrict__ A, const f16* __restrict__ Bt,
    const float* __restrict__ bias, const float* resid, void* outp,
    int N, int K)
{
  __shared__ alignas(16) f16 As[2][128 * 32];
  __shared__ alignas(16) f16 Bs[2][64 * 32];

  int bm, bn;
  tile_map(bm, bn);

  const int tid  = threadIdx.x;
  const int wave = tid >> 6, lane = tid & 63;
  const int quad = lane >> 4, l16 = lane & 15;
  const long tm = (long)bm * 128;
  const long tn = (long)bn * 64;
  const int wm = (wave >> 1) * 64, wn = (wave & 1) * 32;

  const f16* asrc[2];
  const f16* bsrc;
  #pragma unroll
  for (int h = 0; h < 2; ++h) {
    int c = h * 256 + tid;
    long row = c >> 2;
    int jslot = c & 3;
    asrc[h] = A + (tm + row) * K + ((jslot ^ ((row >> 1) & 3)) << 3);
  }
  {
    int c = tid;
    long row = c >> 2;
    int jslot = c & 3;
    bsrc = Bt + (tn + row) * K + ((jslot ^ ((row >> 1) & 3)) << 3);
  }
  int aoff[4], boff[2];
  #pragma unroll
  for (int i = 0; i < 4; ++i) {
    int arow = wm + i * 16 + l16;
    aoff[i] = arow * 32 + ((quad ^ ((arow >> 1) & 3)) << 3);
  }
  #pragma unroll
  for (int j = 0; j < 2; ++j) {
    int brow = wn + j * 16 + l16;
    boff[j] = brow * 32 + ((quad ^ ((brow >> 1) & 3)) << 3);
  }

  v4f acc[4][2];
  #pragma unroll
  for (int i = 0; i < 4; ++i)
    #pragma unroll
    for (int j = 0; j < 2; ++j)
      #pragma unroll
      for (int r = 0; r < 4; ++r) acc[i][j][r] = 0.f;

  const int nt = K >> 5;

#define STAGE_64(buf, t)                                                   \
  {                                                                        \
    const long ko_ = (long)(t) << 5;                                       \
    _Pragma("unroll")                                                      \
    for (int h_ = 0; h_ < 2; ++h_)                                         \
      g2l16(asrc[h_] + ko_, As[buf] + (h_ * 256 + wave * 64) * 8);         \
    g2l16(bsrc + ko_, Bs[buf] + (wave * 64) * 8);                          \
  }

  STAGE_64(0, 0)
  STAGE_64(1, 1)
  asm volatile("s_waitcnt vmcnt(3)" ::: "memory");
  __builtin_amdgcn_s_barrier();

  int cur = 0;
  for (int t = 0; t < nt; ++t) {
    v8h a[4], b[2];
    #pragma unroll
    for (int i = 0; i < 4; ++i) a[i] = *(const v8h*)(As[cur] + aoff[i]);
    #pragma unroll
    for (int j = 0; j < 2; ++j) b[j] = *(const v8h*)(Bs[cur] + boff[j]);
    __builtin_amdgcn_s_setprio(1);
    #pragma unroll
    for (int i = 0; i < 4; ++i)
      #pragma unroll
      for (int j = 0; j < 2; ++j)
        acc[i][j] = __builtin_amdgcn_mfma_f32_16x16x32_f16(a[i], b[j], acc[i][j], 0, 0, 0);
    __builtin_amdgcn_s_setprio(0);
    __builtin_amdgcn_sched_barrier(0);
    __builtin_amdgcn_s_barrier();
    if (t + 2 < nt) {
      STAGE_64(cur, t + 2)
      asm volatile("s_waitcnt vmcnt(3)" ::: "memory");
    } else {
      asm volatile("s_waitcnt vmcnt(0)" ::: "memory");
    }
    __builtin_amdgcn_sched_barrier(0);
    __builtin_amdgcn_s_barrier();
    cur ^= 1;
  }

  #pragma unroll
  for (int i = 0; i < 4; ++i)
    #pragma unroll
    for (int r = 0; r < 4; ++r) {
      long row = tm + wm + i * 16 + quad * 4 + r;
      #pragma unroll
      for (int j = 0; j < 2; ++j) {
        long col = tn + wn + j * 16 + l16;
        float v = acc[i][j][r] + bias[col];
        long idx = row * (long)N + col;
        if (EPI == 0)      ((f16*)outp)[idx] = (f16)v;
        else if (EPI == 1) ((float*)outp)[idx] = resid[idx] + v;
        else               ((float*)outp)[idx] = v;
      }
    }
#undef STAGE_64
}

// ---------------------------------------------------------------------------
// Flash attention: grid (L/64, B*H), 256 threads, KVBLK=64. Wave w owns 16
// query rows. All LDS tiles XOR-swizzled (chunk c' at row holds c'^(row&7)).
// ---------------------------------------------------------------------------
__global__ __launch_bounds__(256) void attn_k(const f16* __restrict__ qkv,
                                              f16* __restrict__ attno)
{
  const int qt = (int)gridDim.x - 1 - blockIdx.x;  // heavy causal tiles first
  const int bh = blockIdx.y;
  const int b = bh >> 4, h = bh & 15;
  const int tid = threadIdx.x;
  const int wave = tid >> 6, lane = tid & 63;
  const int quad = lane >> 4, l16 = lane & 15;

  __shared__ alignas(16) f16 Ks[64 * 64];     // [key][dh], chunk-swizzled
  __shared__ alignas(16) f16 Vt[64 * 64];     // [dh][key], chunk-swizzled
  __shared__ alignas(16) f16 Ps[4][16 * 64];  // per-wave P [q][key], swizzled

  const f16* base = qkv + (size_t)b * L_ * 3072 + h * 64;

  // Q A-frags (dh halves): A[m=lane&15][k=quad*8+j]
  const int qrow = qt * 64 + wave * 16 + l16;
  const v8h qf0 = *(const v8h*)(base + (size_t)qrow * 3072 + quad * 8);
  const v8h qf1 = *(const v8h*)(base + (size_t)qrow * 3072 + 32 + quad * 8);

  v4f of[4];
  float m_i[4], l_i[4];
  for (int n = 0; n < 4; ++n)
    for (int r = 0; r < 4; ++r) of[n][r] = 0.f;
  for (int r = 0; r < 4; ++r) { m_i[r] = -1e30f; l_i[r] = 0.f; }

  const int nblocks = qt + 1;                 // causal bound, uniform in block

  for (int kb = 0; kb < nblocks; ++kb) {
    const int key0 = kb * 64;
    __syncthreads();
    // K: 64 rows x 8 chunks = 512 chunks, 2/thread via global_load_lds.
    for (int h2 = 0; h2 < 2; ++h2) {
      int c = h2 * 256 + tid;
      int row = c >> 3, jslot = c & 7;
      const f16* ksrc = base + 1024 + (size_t)(key0 + row) * 3072
                        + ((jslot ^ (row & 7)) << 3);
      g2l16(ksrc, Ks + (h2 * 256 + wave * 64) * 8);
    }
    // V: reg-staged transpose into Vt[d][key], swizzled stores.
    for (int h2 = 0; h2 < 2; ++h2) {
      int key = tid >> 2;
      int dc = (tid & 3) + h2 * 4;
      const f16* vsrc = base + 2048 + (size_t)(key0 + key) * 3072 + dc * 8;
      v8h vv = *(const v8h*)vsrc;
      for (int e = 0; e < 8; ++e) {
        int d = dc * 8 + e;
        Vt[d * 64 + (((key >> 3) ^ (d & 7)) << 3) + (key & 7)] = vv[e];
      }
    }
    __syncthreads();

    // S = Q K^T for four 16-key sub-blocks
    v4f sf[4];
    for (int s = 0; s < 4; ++s)
      for (int r = 0; r < 4; ++r) sf[s][r] = 0.f;
    for (int s = 0; s < 4; ++s) {
      int krow = s * 16 + l16;
      v8h kf0 = *(const v8h*)(Ks + krow * 64 + ((quad       ^ (krow & 7)) << 3));
      v8h kf1 = *(const v8h*)(Ks + krow * 64 + (((4 + quad) ^ (krow & 7)) << 3));
      sf[s] = __builtin_amdgcn_mfma_f32_16x16x32_f16(qf0, kf0, sf[s], 0, 0, 0);
      sf[s] = __builtin_amdgcn_mfma_f32_16x16x32_f16(qf1, kf1, sf[s], 0, 0, 0);
    }

    const int qg0 = qt * 64 + wave * 16 + quad * 4;
    float pv[4][4];
    for (int s = 0; s < 4; ++s)
      for (int r = 0; r < 4; ++r) {
        float sc = sf[s][r] * 0.125f;              // 1/sqrt(64)
        int kg = key0 + s * 16 + l16;
        if (kg > qg0 + r) sc = -1e30f;             // causal mask
        pv[s][r] = sc;
      }

    for (int r = 0; r < 4; ++r) {
      float mx = fmaxf(fmaxf(pv[0][r], pv[1][r]), fmaxf(pv[2][r], pv[3][r]));
      for (int o = 8; o; o >>= 1) mx = fmaxf(mx, __shfl_xor(mx, o, 64));
      float mnew = fmaxf(m_i[r], mx);
      float alpha = expf(m_i[r] - mnew);
      m_i[r] = mnew;
      float rs = 0.f;
      for (int s = 0; s < 4; ++s) {
        pv[s][r] = expf(pv[s][r] - mnew);
        rs += pv[s][r];
      }
      for (int o = 8; o; o >>= 1) rs += __shfl_xor(rs, o, 64);
      l_i[r] = l_i[r] * alpha + rs;
      for (int n = 0; n < 4; ++n) of[n][r] *= alpha;
      int qr = quad * 4 + r;
      for (int s = 0; s < 4; ++s) {
        int key = s * 16 + l16;
        Ps[wave][qr * 64 + ((((key >> 3)) ^ (qr & 7)) << 3) + (key & 7)]
            = (f16)pv[s][r];
      }
    }
    __syncthreads();   // P C-layout -> A-layout via LDS (and lgkm drain)

    v8h pf0 = *(const v8h*)(&Ps[wave][0] + l16 * 64 + ((quad       ^ (l16 & 7)) << 3));
    v8h pf1 = *(const v8h*)(&Ps[wave][0] + l16 * 64 + (((4 + quad) ^ (l16 & 7)) << 3));
    for (int n = 0; n < 4; ++n) {
      int d = n * 16 + l16;
      v8h vf0 = *(const v8h*)(Vt + d * 64 + ((quad       ^ (d & 7)) << 3));
      v8h vf1 = *(const v8h*)(Vt + d * 64 + (((4 + quad) ^ (d & 7)) << 3));
      of[n] = __builtin_amdgcn_mfma_f32_16x16x32_f16(pf0, vf0, of[n], 0, 0, 0);
      of[n] = __builtin_amdgcn_mfma_f32_16x16x32_f16(pf1, vf1, of[n], 0, 0, 0);
    }
  }

  const int q = qt * 64 + wave * 16 + quad * 4;
  f16* orow = attno + (size_t)b * L_ * 1024 + h * 64;
  for (int r = 0; r < 4; ++r) {
    float inv = 1.0f / l_i[r];
    for (int n = 0; n < 4; ++n)
      orow[(size_t)(q + r) * 1024 + n * 16 + l16] = (f16)(of[n][r] * inv);
  }
}

// ---------------------------------------------------------------------------
// small kernels
// ---------------------------------------------------------------------------
__global__ __launch_bounds__(256) void embed_pe(const int* __restrict__ ids,
                                                const float* __restrict__ emb,
                                                float* __restrict__ x)
{
  const int bl = blockIdx.x;          // 0..4095
  const int l = bl & (L_ - 1);
  const int id = ids[bl];
  const float* e = emb + (size_t)id * D_;
  float* xr = x + (size_t)bl * D_;
  const int d0 = threadIdx.x * 4;
  for (int i = 0; i < 4; ++i) {
    int d = d0 + i;
    int p = d >> 1;
    float ang = (float)l * expf((float)(2 * p) * -0.008994473019508053f); // ln(1e4)/1024
    float pe = (d & 1) ? cosf(ang) : sinf(ang);
    xr[d] = e[d] + pe;
  }
}

__global__ __launch_bounds__(256) void rmsnorm_k(const float* __restrict__ x,
                                                 const float* __restrict__ gamma,
                                                 f16* __restrict__ y)
{
  const int row = blockIdx.x;
  const float4 v = ((const float4*)(x + (size_t)row * D_))[threadIdx.x];
  float s = v.x * v.x + v.y * v.y + v.z * v.z + v.w * v.w;
  for (int o = 32; o; o >>= 1) s += __shfl_xor(s, o, 64);
  __shared__ float red[4];
  const int wave = threadIdx.x >> 6;
  if ((threadIdx.x & 63) == 0) red[wave] = s;
  __syncthreads();
  const float tot = red[0] + red[1] + red[2] + red[3];
  const float scale = rsqrtf(tot * (1.0f / D_) + 1e-6f);
  f16* yr = y + (size_t)row * D_;
  const int d = threadIdx.x * 4;
  yr[d]     = (f16)(v.x * scale * gamma[d]);
  yr[d + 1] = (f16)(v.y * scale * gamma[d + 1]);
  yr[d + 2] = (f16)(v.z * scale * gamma[d + 2]);
  yr[d + 3] = (f16)(v.w * scale * gamma[d + 3]);
}

// f32 [K,N] -> f16 [N,K] (transpose + convert), 32x32 LDS tiles
__global__ __launch_bounds__(256) void transpose_cvt(const float* __restrict__ in,
                                                     f16* __restrict__ out,
                                                     int K, int N)
{
  __shared__ float tile[32][33];
  const int r = threadIdx.x >> 5, c = threadIdx.x & 31;
  const size_t bk = (size_t)blockIdx.y * 32;
  const size_t bn = (size_t)blockIdx.x * 32;
  for (int i = 0; i < 32; i += 8)
    tile[r + i][c] = in[(bk + r + i) * N + bn + c];
  __syncthreads();
  for (int i = 0; i < 32; i += 8)
    out[(bn + r + i) * K + bk + c] = (f16)tile[c][r + i];
}

__global__ __launch_bounds__(256) void gate_k(const f16* __restrict__ PU,
                                              f16* __restrict__ g)
{
  const int e = (blockIdx.x * 256 + threadIdx.x) * 4;
  const int row = e >> 11, col = e & 2047;
  const f16* p = PU + (size_t)row * 4096 + col;
  const f16* u = p + 2048;
  f16* go = g + (size_t)row * 2048 + col;
  for (int i = 0; i < 4; ++i) {
    float z = (float)p[i] * (float)u[i];
    go[i] = (f16)(z / (1.0f + expf(-z)));
  }
}

__global__ __launch_bounds__(256) void cast_k(const float* __restrict__ x,
                                              f16* __restrict__ y)
{
  const int i = blockIdx.x * 1024 + threadIdx.x * 4;
  const float4 v = *(const float4*)(x + i);
  y[i] = (f16)v.x; y[i + 1] = (f16)v.y; y[i + 2] = (f16)v.z; y[i + 3] = (f16)v.w;
}

__global__ __launch_bounds__(256) void build_biases(
    const float* bq, const float* bk, const float* bv,
    const float* bp, const float* bu, float* bqkv, float* bpu)
{
  const int i = blockIdx.x;
  for (int j = threadIdx.x; j < 3072; j += 256)
    bqkv[i * 3072 + j] = j < 1024 ? bq[i * 1024 + j]
                       : j < 2048 ? bk[i * 1024 + j - 1024]
                                  : bv[i * 1024 + j - 2048];
  for (int j = threadIdx.x; j < 4096; j += 256)
    bpu[i * 4096 + j] = j < 2048 ? bp[i * 2048 + j] : bu[i * 2048 + j - 2048];
}

// ---------------------------------------------------------------------------
extern "C" void kernel_launch(void* const* d_in, const int* in_sizes, int n_in,
                              void* d_out, int out_size, void* d_ws, size_t ws_size,
                              hipStream_t stream)
{
  (void)in_sizes; (void)n_in; (void)out_size; (void)ws_size;
  const int*   ids     = (const int*)  d_in[0];
  const float* embed   = (const float*)d_in[1];
  const float* Wq      = (const float*)d_in[2];
  const float* bq      = (const float*)d_in[3];
  const float* Wk      = (const float*)d_in[4];
  const float* bk      = (const float*)d_in[5];
  const float* Wv      = (const float*)d_in[6];
  const float* bv      = (const float*)d_in[7];
  const float* Wo      = (const float*)d_in[8];
  const float* bo      = (const float*)d_in[9];
  const float* Wproj   = (const float*)d_in[10];
  const float* bproj   = (const float*)d_in[11];
  const float* Wup     = (const float*)d_in[12];
  const float* bup     = (const float*)d_in[13];
  const float* Wdown   = (const float*)d_in[14];
  const float* bdown   = (const float*)d_in[15];
  const float* gammas  = (const float*)d_in[16];
  const float* Wlogits = (const float*)d_in[17];
  const float* blogits = (const float*)d_in[18];

  char* ws = (char*)d_ws;
  float* x    = (float*)ws;                       // 16,777,216 B
  f16*   y    = (f16*)  (ws + 16777216);          //  8,388,608 B
  float* bqkv = (float*)(ws + 25165824);          //     49,152 B
  float* bpu  = (float*)(ws + 25214976);          //     65,536 B
  f16*   wbuf = (f16*)  (ws + 25280512);          // 65,536,000 B (WlogitsT max)
  f16* wqkvT  = wbuf;                 // [3072][1024]
  f16* woT    = wbuf + 3145728;       // [1024][1024]
  f16* wpuT   = wbuf + 4194304;       // [4096][1024]
  f16* wdownT = wbuf + 8388608;       // [1024][2048]

  // transient activations live in d_out until the final logits GEMM
  char* ob  = (char*)d_out;
  f16* qkv   = (f16*)ob;               // [4096][3072] 25,165,824 B
  f16* attno = (f16*)(ob + 25165824);  // [4096][1024]  8,388,608 B
  f16* PU    = (f16*)(ob + 33554432);  // [4096][4096] 33,554,432 B
  f16* g     = (f16*)(ob + 67108864);  // [4096][2048] 16,777,216 B

  embed_pe<<<M_, 256, 0, stream>>>(ids, embed, x);
  build_biases<<<4, 256, 0, stream>>>(bq, bk, bv, bproj, bup, bqkv, bpu);

  for (int i = 0; i < 4; ++i) {
    const float* Wqi = Wq + (size_t)i * 1048576;
    const float* Wki = Wk + (size_t)i * 1048576;
    const float* Wvi = Wv + (size_t)i * 1048576;
    const float* Woi = Wo + (size_t)i * 1048576;
    const float* Wpi = Wproj + (size_t)i * 2097152;
    const float* Wui = Wup   + (size_t)i * 2097152;
    const float* Wdi = Wdown + (size_t)i * 2097152;

    transpose_cvt<<<dim3(32, 32), 256, 0, stream>>>(Wqi, wqkvT,                1024, 1024);
    transpose_cvt<<<dim3(32, 32), 256, 0, stream>>>(Wki, wqkvT + 1048576,      1024, 1024);
    transpose_cvt<<<dim3(32, 32), 256, 0, stream>>>(Wvi, wqkvT + 2097152,      1024, 1024);
    transpose_cvt<<<dim3(32, 32), 256, 0, stream>>>(Woi, woT,                  1024, 1024);
    transpose_cvt<<<dim3(64, 32), 256, 0, stream>>>(Wpi, wpuT,                 1024, 2048);
    transpose_cvt<<<dim3(64, 32), 256, 0, stream>>>(Wui, wpuT + 2097152,       1024, 2048);
    transpose_cvt<<<dim3(32, 64), 256, 0, stream>>>(Wdi, wdownT,               2048, 1024);

    rmsnorm_k<<<M_, 256, 0, stream>>>(x, gammas + (size_t)(2 * i) * 1024, y);
    gemm_wt<0><<<dim3(16, 24), 256, 0, stream>>>(y, wqkvT, bqkv + i * 3072, nullptr, qkv, 3072, 1024);
    attn_k<<<dim3(32, 32), 256, 0, stream>>>(qkv, attno);
    gemm64_bt<1><<<dim3(32, 16), 256, 0, stream>>>(attno, woT, bo + i * 1024, x, x, 1024, 1024);

    rmsnorm_k<<<M_, 256, 0, stream>>>(x, gammas + (size_t)(2 * i + 1) * 1024, y);
    gemm_wt<0><<<dim3(16, 32), 256, 0, stream>>>(y, wpuT, bpu + i * 4096, nullptr, PU, 4096, 1024);
    gate_k<<<8192, 256, 0, stream>>>(PU, g);
    gemm64_bt<1><<<dim3(32, 16), 256, 0, stream>>>(g, wdownT, bdown + i * 1024, x, x, 1024, 2048);
  }

  transpose_cvt<<<dim3(1000, 32), 256, 0, stream>>>(Wlogits, wbuf, 1024, 32000);
  cast_k<<<M_, 256, 0, stream>>>(x, y);
  gemm_wt<2><<<dim3(16, 250), 256, 0, stream>>>(y, wbuf, blogits, nullptr, (float*)d_out, 32000, 1024);
}